// Round 2
// baseline (2977.878 us; speedup 1.0000x reference)
//
#include <hip/hip_runtime.h>
#include <hip/hip_bf16.h>
#include <math.h>

#define SEQ 70
#define HID 230
#define G3  690
#define EMBD 50
#define DIN 60
#define NTOT 2048
#define NREL 100
#define NBAG 64
#define BAGSZ 32
#define PDIM 5
#define MBS 16   // sentences per GRU block

// ---------------- prep kernels ----------------

__global__ void k_zero(float* p, long n) {
    long i = (long)blockIdx.x * 256 + threadIdx.x;
    if (i < n) p[i] = 0.f;
}

__global__ void k_embed(const int* __restrict__ sent, const int* __restrict__ p1,
                        const int* __restrict__ p2,  const float* __restrict__ wemb,
                        const float* __restrict__ t1, const float* __restrict__ t2,
                        float* __restrict__ emb) {
    long idx = (long)blockIdx.x * 256 + threadIdx.x;
    long total = (long)NTOT * SEQ * DIN;
    if (idx >= total) return;
    int nt = (int)(idx / DIN);
    int j  = (int)(idx % DIN);
    float v;
    if (j < EMBD)             v = wemb[(long)sent[nt] * EMBD + j];
    else if (j < EMBD + PDIM) v = t1[p1[nt] * PDIM + (j - EMBD)];
    else                      v = t2[p2[nt] * PDIM + (j - EMBD - PDIM)];
    emb[idx] = v;
}

// in[g*K+k] -> out[k*G+g]
__global__ void k_transpose(const float* __restrict__ in, float* __restrict__ out,
                            int G, int K) {
    int idx = blockIdx.x * 256 + threadIdx.x;
    if (idx >= G * K) return;
    int g = idx / K, k = idx % K;
    out[k * G + g] = in[idx];
}

// ---------------- GRU (both directions in one launch) ----------------
// grid = (NTOT/MBS)*2 = 256 blocks, 256 threads. blockIdx.x&1 = direction.
// tup zeroed beforehand; both directions atomicAdd into it.
__global__ __launch_bounds__(256) void k_gru(
    const float* __restrict__ emb,
    const float* __restrict__ wihT_f, const float* __restrict__ whhT_f,
    const float* __restrict__ bih_f,  const float* __restrict__ bhh_f,
    const float* __restrict__ wihT_b, const float* __restrict__ whhT_b,
    const float* __restrict__ bih_b,  const float* __restrict__ bhh_b,
    float* __restrict__ tup) {

    const bool rev = blockIdx.x & 1;
    const int  n0  = (blockIdx.x >> 1) * MBS;
    const float* wihT = rev ? wihT_b : wihT_f;
    const float* whhT = rev ? whhT_b : whhT_f;
    const float* bih  = rev ? bih_b  : bih_f;
    const float* bhh  = rev ? bhh_b  : bhh_f;
    const int tid = threadIdx.x;

    __shared__ float h_s[HID * MBS];   // [k][n]  14720 B
    __shared__ float e_s[DIN * MBS];   // [k][n]   3840 B
    __shared__ float P_s[G3 * MBS];    // gate pre-activations         44160 B
    __shared__ float Q_s[HID * MBS];   // h_n part of n-gate           14720 B

    for (int i = tid; i < HID * MBS; i += 256) h_s[i] = 0.f;

    const int g0 = tid;            // [0,256)   r or z gate
    const int g1 = tid + 256;      // [256,512) z or n gate
    const int g2 = tid + 512;      // [512,690) n gate; valid if < 690
    const bool v2 = (g2 < G3);
    const int g2s = v2 ? g2 : 0;   // safe index for loads

    const float bi0 = bih[g0], bh0 = bhh[g0];
    const float bi1 = bih[g1], bh1 = bhh[g1];
    const float bi2 = v2 ? bih[g2] : 0.f, bh2 = v2 ? bhh[g2] : 0.f;

    const float* wi0 = wihT + g0;
    const float* wi1 = wihT + g1;
    const float* wi2 = wihT + g2s;
    const float* wh0 = whhT + g0;
    const float* wh1 = whhT + g1;
    const float* wh2 = whhT + g2s;

    for (int t = 0; t < SEQ; ++t) {
        const int tt = rev ? (SEQ - 1 - t) : t;

        // stage emb tile [60][16] with float4 loads (row = 15 float4)
        if (tid < 240) {
            int n = tid / 15, q = tid - n * 15;
            const float4 v = *(const float4*)&emb[((long)(n0 + n) * SEQ + tt) * DIN + q * 4];
            int k = q * 4;
            e_s[(k + 0) * MBS + n] = v.x;
            e_s[(k + 1) * MBS + n] = v.y;
            e_s[(k + 2) * MBS + n] = v.z;
            e_s[(k + 3) * MBS + n] = v.w;
        }
        __syncthreads();   // S1: h_s (prev combine) + e_s visible

        float a0[MBS], a1[MBS], a2[MBS], h0[MBS], h1[MBS], h2[MBS];
#pragma unroll
        for (int n = 0; n < MBS; ++n) {
            a0[n] = bi0; a1[n] = bi1; a2[n] = bi2;
            h0[n] = bh0; h1[n] = bh1; h2[n] = bh2;
        }
        // input projection, K = 60
#pragma unroll 4
        for (int k = 0; k < DIN; ++k) {
            float w0 = wi0[(size_t)k * G3];
            float w1 = wi1[(size_t)k * G3];
            float w2 = wi2[(size_t)k * G3];
            const float4* ep = (const float4*)&e_s[k * MBS];
            float4 e0 = ep[0], e1 = ep[1], e2 = ep[2], e3 = ep[3];
            float ev[MBS] = {e0.x, e0.y, e0.z, e0.w, e1.x, e1.y, e1.z, e1.w,
                             e2.x, e2.y, e2.z, e2.w, e3.x, e3.y, e3.z, e3.w};
#pragma unroll
            for (int n = 0; n < MBS; ++n) {
                a0[n] = fmaf(w0, ev[n], a0[n]);
                a1[n] = fmaf(w1, ev[n], a1[n]);
                a2[n] = fmaf(w2, ev[n], a2[n]);
            }
        }
        // hidden projection, K = 230
#pragma unroll 4
        for (int k = 0; k < HID; ++k) {
            float w0 = wh0[(size_t)k * G3];
            float w1 = wh1[(size_t)k * G3];
            float w2 = wh2[(size_t)k * G3];
            const float4* hp = (const float4*)&h_s[k * MBS];
            float4 x0 = hp[0], x1 = hp[1], x2 = hp[2], x3 = hp[3];
            float hv[MBS] = {x0.x, x0.y, x0.z, x0.w, x1.x, x1.y, x1.z, x1.w,
                             x2.x, x2.y, x2.z, x2.w, x3.x, x3.y, x3.z, x3.w};
#pragma unroll
            for (int n = 0; n < MBS; ++n) {
                h0[n] = fmaf(w0, hv[n], h0[n]);
                h1[n] = fmaf(w1, hv[n], h1[n]);
                h2[n] = fmaf(w2, hv[n], h2[n]);
            }
        }
        // publish gate pre-activations (contiguous float4 stores per gate)
        {
            float4* p0 = (float4*)&P_s[g0 * MBS];
#pragma unroll
            for (int j = 0; j < 4; ++j)
                p0[j] = make_float4(a0[4*j] + h0[4*j], a0[4*j+1] + h0[4*j+1],
                                    a0[4*j+2] + h0[4*j+2], a0[4*j+3] + h0[4*j+3]);
        }
        if (g1 < 2 * HID) {
            float4* p1 = (float4*)&P_s[g1 * MBS];
#pragma unroll
            for (int j = 0; j < 4; ++j)
                p1[j] = make_float4(a1[4*j] + h1[4*j], a1[4*j+1] + h1[4*j+1],
                                    a1[4*j+2] + h1[4*j+2], a1[4*j+3] + h1[4*j+3]);
        } else {
            float4* p1 = (float4*)&P_s[g1 * MBS];
            float4* q1 = (float4*)&Q_s[(g1 - 2 * HID) * MBS];
#pragma unroll
            for (int j = 0; j < 4; ++j) {
                p1[j] = make_float4(a1[4*j], a1[4*j+1], a1[4*j+2], a1[4*j+3]);
                q1[j] = make_float4(h1[4*j], h1[4*j+1], h1[4*j+2], h1[4*j+3]);
            }
        }
        if (v2) {
            float4* p2 = (float4*)&P_s[g2 * MBS];
            float4* q2 = (float4*)&Q_s[(g2 - 2 * HID) * MBS];
#pragma unroll
            for (int j = 0; j < 4; ++j) {
                p2[j] = make_float4(a2[4*j], a2[4*j+1], a2[4*j+2], a2[4*j+3]);
                q2[j] = make_float4(h2[4*j], h2[4*j+1], h2[4*j+2], h2[4*j+3]);
            }
        }
        __syncthreads();   // S2

        // combine gates -> new h, write to tup.
        // e == hh*MBS + n directly: consecutive lanes -> consecutive LDS
        // addresses -> conflict-free.
        for (int e = tid; e < HID * MBS; e += 256) {
            int n = e & (MBS - 1), hh = e >> 4;
            float r  = 1.f / (1.f + expf(-P_s[e]));
            float z  = 1.f / (1.f + expf(-P_s[HID * MBS + e]));
            float nn = tanhf(P_s[2 * HID * MBS + e] + r * Q_s[e]);
            float hold = h_s[e];
            float hnew = (1.f - z) * nn + z * hold;
            h_s[e] = hnew;
            atomicAdd(&tup[((long)(n0 + n) * SEQ + tt) * HID + hh], hnew);
        }
    }
}

// ---------------- word-level attention ----------------
__global__ __launch_bounds__(256) void k_wordattn(
    const float* __restrict__ tup, const float* __restrict__ attw,
    const float* __restrict__ sen_a, const float* __restrict__ sen_r,
    float* __restrict__ repre, float* __restrict__ sbuf) {
    const int n = blockIdx.x, tid = threadIdx.x;
    __shared__ float tl[SEQ * HID];   // 64400 B
    __shared__ float sc[SEQ];
    __shared__ float red[4];
    for (int i = tid; i < SEQ * HID; i += 256) tl[i] = tup[(long)n * SEQ * HID + i];
    __syncthreads();
    if (tid < SEQ) {
        float s = 0.f;
        for (int h = 0; h < HID; ++h) s += tanhf(tl[tid * HID + h]) * attw[h];
        sc[tid] = s;
    }
    __syncthreads();
    if (tid == 0) {
        float m = sc[0];
        for (int t = 1; t < SEQ; ++t) m = fmaxf(m, sc[t]);
        float ssum = 0.f;
        for (int t = 0; t < SEQ; ++t) { float e = expf(sc[t] - m); sc[t] = e; ssum += e; }
        float inv = 1.f / ssum;
        for (int t = 0; t < SEQ; ++t) sc[t] *= inv;
    }
    __syncthreads();
    float part = 0.f;
    if (tid < HID) {
        float r = 0.f;
        for (int t = 0; t < SEQ; ++t) r = fmaf(sc[t], tl[t * HID + tid], r);
        float rep = tanhf(r);
        repre[(long)n * HID + tid] = rep;
        part = rep * sen_a[tid] * sen_r[tid];
    }
    for (int off = 32; off; off >>= 1) part += __shfl_down(part, off, 64);
    if ((tid & 63) == 0) red[tid >> 6] = part;
    __syncthreads();
    if (tid == 0) sbuf[n] = red[0] + red[1] + red[2] + red[3];
}

// ---------------- bag attention + logits + loss + prob + acc ----------------
__global__ __launch_bounds__(256) void k_bag(
    const float* __restrict__ repre, const float* __restrict__ sbuf,
    const float* __restrict__ rel, const float* __restrict__ sen_d,
    const float* __restrict__ y, float* __restrict__ out, float* __restrict__ bagloss) {
    const int b = blockIdx.x, tid = threadIdx.x;
    __shared__ float al[BAGSZ];
    __shared__ float ss[HID];
    __shared__ float lg[NREL];
    if (tid == 0) {
        float m = -1e30f;
        for (int i = 0; i < BAGSZ; ++i) m = fmaxf(m, sbuf[b * BAGSZ + i]);
        float s = 0.f;
        for (int i = 0; i < BAGSZ; ++i) { float e = expf(sbuf[b * BAGSZ + i] - m); al[i] = e; s += e; }
        float inv = 1.f / s;
        for (int i = 0; i < BAGSZ; ++i) al[i] *= inv;
    }
    __syncthreads();
    if (tid < HID) {
        float acc = 0.f;
        for (int i = 0; i < BAGSZ; ++i)
            acc = fmaf(al[i], repre[(long)(b * BAGSZ + i) * HID + tid], acc);
        ss[tid] = acc;
    }
    __syncthreads();
    if (tid < NREL) {
        float acc = sen_d[tid];
        for (int h = 0; h < HID; ++h) acc = fmaf(ss[h], rel[tid * HID + h], acc);
        lg[tid] = acc;
    }
    __syncthreads();
    if (tid == 0) {
        float m = -1e30f; int am = 0;
        for (int r = 0; r < NREL; ++r) if (lg[r] > m) { m = lg[r]; am = r; }
        float s = 0.f;
        for (int r = 0; r < NREL; ++r) s += expf(lg[r] - m);
        float inv = 1.f / s;
        float ym = -1e30f; int ay = 0;
        for (int r = 0; r < NREL; ++r) { float yy = y[b * NREL + r]; if (yy > ym) { ym = yy; ay = r; } }
        out[1 + b] = (am == ay) ? 1.f : 0.f;
        float loss = 0.f;
        for (int r = 0; r < NREL; ++r) {
            float l = lg[r], yy = y[b * NREL + r];
            loss += fmaxf(l, 0.f) - l * yy + log1pf(expf(-fabsf(l)));
            out[1 + NBAG + b * NREL + r] = expf(l - m) * inv;
        }
        bagloss[b] = loss / NREL;
    }
}

__global__ void k_final(const float* __restrict__ bagloss, float* __restrict__ out) {
    if (blockIdx.x == 0 && threadIdx.x == 0) {
        float s = 0.f;
        for (int i = 0; i < NBAG; ++i) s += bagloss[i];
        out[0] = s;
    }
}

// ---------------- host launcher ----------------
extern "C" void kernel_launch(void* const* d_in, const int* in_sizes, int n_in,
                              void* d_out, int out_size, void* d_ws, size_t ws_size,
                              hipStream_t stream) {
    const int*   sent   = (const int*)d_in[0];
    const int*   pos1   = (const int*)d_in[1];
    const int*   pos2   = (const int*)d_in[2];
    const float* ybatch = (const float*)d_in[4];
    const float* wemb   = (const float*)d_in[5];
    const float* p1tab  = (const float*)d_in[6];
    const float* p2tab  = (const float*)d_in[7];
    const float* Wih_f  = (const float*)d_in[8];
    const float* Whh_f  = (const float*)d_in[9];
    const float* bih_f  = (const float*)d_in[10];
    const float* bhh_f  = (const float*)d_in[11];
    const float* Wih_b  = (const float*)d_in[12];
    const float* Whh_b  = (const float*)d_in[13];
    const float* bih_b  = (const float*)d_in[14];
    const float* bhh_b  = (const float*)d_in[15];
    const float* attw   = (const float*)d_in[16];
    const float* sen_a  = (const float*)d_in[17];
    const float* sen_r  = (const float*)d_in[18];
    const float* rel    = (const float*)d_in[19];
    const float* sen_d  = (const float*)d_in[20];
    float* out = (float*)d_out;

    float* ws = (float*)d_ws;
    size_t off = 0;
    float* emb    = ws + off; off += (size_t)NTOT * SEQ * DIN;
    float* wihT_f = ws + off; off += (size_t)DIN * G3;
    float* wihT_b = ws + off; off += (size_t)DIN * G3;
    float* whhT_f = ws + off; off += (size_t)HID * G3;
    float* whhT_b = ws + off; off += (size_t)HID * G3;
    float* tup    = ws + off; off += (size_t)NTOT * SEQ * HID;
    float* repre  = ws + off; off += (size_t)NTOT * HID;
    float* sbuf   = ws + off; off += (size_t)NTOT;
    float* bagloss= ws + off; off += (size_t)NBAG;

    const long tupN = (long)NTOT * SEQ * HID;
    k_zero<<<(int)((tupN + 255) / 256), 256, 0, stream>>>(tup, tupN);

    const long embN = (long)NTOT * SEQ * DIN;
    k_embed<<<(int)((embN + 255) / 256), 256, 0, stream>>>(sent, pos1, pos2, wemb, p1tab, p2tab, emb);

    k_transpose<<<(G3 * DIN + 255) / 256, 256, 0, stream>>>(Wih_f, wihT_f, G3, DIN);
    k_transpose<<<(G3 * DIN + 255) / 256, 256, 0, stream>>>(Wih_b, wihT_b, G3, DIN);
    k_transpose<<<(G3 * HID + 255) / 256, 256, 0, stream>>>(Whh_f, whhT_f, G3, HID);
    k_transpose<<<(G3 * HID + 255) / 256, 256, 0, stream>>>(Whh_b, whhT_b, G3, HID);

    k_gru<<<(NTOT / MBS) * 2, 256, 0, stream>>>(emb,
        wihT_f, whhT_f, bih_f, bhh_f,
        wihT_b, whhT_b, bih_b, bhh_b, tup);

    k_wordattn<<<NTOT, 256, 0, stream>>>(tup, attw, sen_a, sen_r, repre, sbuf);

    k_bag<<<NBAG, 256, 0, stream>>>(repre, sbuf, rel, sen_d, ybatch, out, bagloss);

    k_final<<<1, 64, 0, stream>>>(bagloss, out);
}